// Round 13
// baseline (125.893 us; speedup 1.0000x reference)
//
#include <hip/hip_runtime.h>

#define NB 8          // 7 full blocks + 1 partial block
#define DDIM 2048
#define THREADS 256

typedef float f32x4 __attribute__((ext_vector_type(4)));

// 64-lane f32 add-reduction via DPP (VALU pipe, no DS ops). Total in lane 63.
__device__ __forceinline__ float wave_sum64(float x) {
    int t;
    t = __builtin_amdgcn_update_dpp(0, __float_as_int(x), 0x111, 0xf, 0xf, false); // row_shr:1
    x += __int_as_float(t);
    t = __builtin_amdgcn_update_dpp(0, __float_as_int(x), 0x112, 0xf, 0xf, false); // row_shr:2
    x += __int_as_float(t);
    t = __builtin_amdgcn_update_dpp(0, __float_as_int(x), 0x114, 0xf, 0xf, false); // row_shr:4
    x += __int_as_float(t);
    t = __builtin_amdgcn_update_dpp(0, __float_as_int(x), 0x118, 0xf, 0xf, false); // row_shr:8
    x += __int_as_float(t);
    t = __builtin_amdgcn_update_dpp(0, __float_as_int(x), 0x142, 0xa, 0xf, false); // row_bcast:15
    x += __int_as_float(t);
    t = __builtin_amdgcn_update_dpp(0, __float_as_int(x), 0x143, 0xc, 0xf, false); // row_bcast:31
    x += __int_as_float(t);
    return x;
}

__global__ __launch_bounds__(THREADS, 4)   // cap at 128 VGPR -> 4 blocks/CU
void block_attn_res_kernel(
    const float* __restrict__ blocks,   // [7, B*T, D]
    const float* __restrict__ partial,  // [B*T, D]
    const float* __restrict__ qa,
    const float* __restrict__ qm,
    const float* __restrict__ wa,
    const float* __restrict__ wm,
    float* __restrict__ out,            // h_attn [B*T*D] then h_mlp [B*T*D]
    int BT)
{
    const int row = blockIdx.x;
    const int tid = threadIdx.x;
    // two fully-coalesced column groups: [4*tid, 4*tid+4) and +D/2
    const int c0 = tid * 4;
    const int c1 = c0 + DDIM / 2;

    const size_t rowBase = (size_t)row * DDIM;
    const size_t nStride = (size_t)BT * DDIM;

    // per-thread q*w slice (16 VGPR)
    f32x4 qw[2][2];   // [a/m][half]
    {
        const f32x4 qa0 = *reinterpret_cast<const f32x4*>(qa + c0);
        const f32x4 qa1 = *reinterpret_cast<const f32x4*>(qa + c1);
        const f32x4 wa0 = *reinterpret_cast<const f32x4*>(wa + c0);
        const f32x4 wa1 = *reinterpret_cast<const f32x4*>(wa + c1);
        const f32x4 qm0 = *reinterpret_cast<const f32x4*>(qm + c0);
        const f32x4 qm1 = *reinterpret_cast<const f32x4*>(qm + c1);
        const f32x4 wm0 = *reinterpret_cast<const f32x4*>(wm + c0);
        const f32x4 wm1 = *reinterpret_cast<const f32x4*>(wm + c1);
        qw[0][0] = qa0 * wa0;  qw[0][1] = qa1 * wa1;
        qw[1][0] = qm0 * wm0;  qw[1][1] = qm1 * wm1;
    }

    // register-resident V slice: 8 n-rows x 8 floats = 64 VGPR
    f32x4 v[NB][2];
    float ss[NB], da[NB], dm[NB];

#pragma unroll
    for (int n = 0; n < NB; ++n) {
        const float* src = (n < NB - 1) ? (blocks + (size_t)n * nStride + rowBase)
                                        : (partial + rowBase);
        v[n][0] = *reinterpret_cast<const f32x4*>(src + c0);
        v[n][1] = *reinterpret_cast<const f32x4*>(src + c1);
        float s = 0.f, pa = 0.f, pm = 0.f;
#pragma unroll
        for (int k = 0; k < 2; ++k) {
#pragma unroll
            for (int j = 0; j < 4; ++j) {
                s  += v[n][k][j]  * v[n][k][j];
                pa += qw[0][k][j] * v[n][k][j];
                pm += qw[1][k][j] * v[n][k][j];
            }
        }
        ss[n] = s; da[n] = pa; dm[n] = pm;
    }

    // wave-level reduction entirely on the VALU pipe (DPP); result in lane 63
#pragma unroll
    for (int n = 0; n < NB; ++n) {
        ss[n] = wave_sum64(ss[n]);
        da[n] = wave_sum64(da[n]);
        dm[n] = wave_sum64(dm[n]);
    }

    // cross-wave combine: 24 floats per wave, [wave][24] layout
    __shared__ float red[4 * 24];
    const int wave = tid >> 6;
    if ((tid & 63) == 63) {
#pragma unroll
        for (int n = 0; n < NB; ++n) {
            red[wave * 24 + n]      = ss[n];
            red[wave * 24 + 8 + n]  = da[n];
            red[wave * 24 + 16 + n] = dm[n];
        }
    }
    __syncthreads();

    // sum the 4 per-wave partial vectors with vector ds_read_b128 (broadcast)
    float tot[24];
    {
        const f32x4* r4 = reinterpret_cast<const f32x4*>(red);
#pragma unroll
        for (int g = 0; g < 6; ++g) {
            f32x4 a = r4[g], b = r4[6 + g], c = r4[12 + g], d = r4[18 + g];
            f32x4 s4 = a + b + c + d;
            tot[4 * g + 0] = s4.x;
            tot[4 * g + 1] = s4.y;
            tot[4 * g + 2] = s4.z;
            tot[4 * g + 3] = s4.w;
        }
    }

    float aw[NB], mw[NB];
    {
        const float inv_sqrt_d = rsqrtf((float)DDIM);
        float lga[NB], lgm[NB];
#pragma unroll
        for (int n = 0; n < NB; ++n) {
            float rms = rsqrtf(tot[n] * (1.0f / DDIM) + 1e-6f);
            lga[n] = tot[8 + n]  * rms * inv_sqrt_d;
            lgm[n] = tot[16 + n] * rms * inv_sqrt_d;
        }
        float ma = lga[0], mm = lgm[0];
#pragma unroll
        for (int n = 1; n < NB; ++n) { ma = fmaxf(ma, lga[n]); mm = fmaxf(mm, lgm[n]); }
        float sa = 0.f, sm = 0.f;
#pragma unroll
        for (int n = 0; n < NB; ++n) {
            aw[n] = __expf(lga[n] - ma); sa += aw[n];
            mw[n] = __expf(lgm[n] - mm); sm += mw[n];
        }
        const float ra = 1.f / sa, rm = 1.f / sm;
#pragma unroll
        for (int n = 0; n < NB; ++n) { aw[n] *= ra; mw[n] *= rm; }
    }

    // combine straight from registers — V read from HBM exactly once
    f32x4 oa[2], om[2];
#pragma unroll
    for (int k = 0; k < 2; ++k) {
        oa[k] = (f32x4)(0.f);
        om[k] = (f32x4)(0.f);
    }
#pragma unroll
    for (int n = 0; n < NB; ++n) {
#pragma unroll
        for (int k = 0; k < 2; ++k) {
            oa[k] += aw[n] * v[n][k];
            om[k] += mw[n] * v[n][k];
        }
    }

    // NT stores ONLY (loads stay cached): write around L2 so the output
    // stream doesn't evict/steal L2 resources from the 537 MB read stream.
    float* outa = out + rowBase;
    float* outm = out + nStride + rowBase;
    __builtin_nontemporal_store(oa[0], reinterpret_cast<f32x4*>(outa + c0));
    __builtin_nontemporal_store(oa[1], reinterpret_cast<f32x4*>(outa + c1));
    __builtin_nontemporal_store(om[0], reinterpret_cast<f32x4*>(outm + c0));
    __builtin_nontemporal_store(om[1], reinterpret_cast<f32x4*>(outm + c1));
}

extern "C" void kernel_launch(void* const* d_in, const int* in_sizes, int n_in,
                              void* d_out, int out_size, void* d_ws, size_t ws_size,
                              hipStream_t stream)
{
    const float* blocks  = (const float*)d_in[0];
    const float* partial = (const float*)d_in[1];
    const float* qa      = (const float*)d_in[2];
    const float* qm      = (const float*)d_in[3];
    const float* wa      = (const float*)d_in[4];
    const float* wm      = (const float*)d_in[5];
    float* out = (float*)d_out;

    const int D  = in_sizes[2];          // 2048
    const int BT = in_sizes[1] / D;      // B*T = 8192

    dim3 grid(BT), block(THREADS);
    hipLaunchKernelGGL(block_attn_res_kernel, grid, block, 0, stream,
                       blocks, partial, qa, qm, wa, wm, out, BT);
}